// Round 9
// baseline (111.636 us; speedup 1.0000x reference)
//
#include <hip/hip_runtime.h>

// VectorQuantizer: N=65536 rows x D=64, K=1024 codes.
// argmin_k ||x - e_k||^2 == argmin_k ( ||e_k||^2 - 2 x.e_k )
// R7: 16x16x32 MFMA, 16 rows/wave -> 4096 waves = 16 waves/CU (2x TLP of R6),
// 4 blocks/CU. Pre-packed pre-swizzled bf16 codebook DMA'd in 128-code
// double-buffered chunks (global_load_lds, zero VALU staging).

#define NROWS 65536
#define DDIM 64
#define KEMB 1024
#define KCHUNK 128
#define NCHUNKS (KEMB / KCHUNK)            // 8
#define BLKTHREADS 256                     // 4 waves
#define ROWS_PER_BLOCK 64                  // 16 rows/wave
#define NBLOCKS (NROWS / ROWS_PER_BLOCK)   // 1024 -> 4 blocks/CU
#define CHUNK_BYTES (KCHUNK * 128)         // 16384
#define P_OFF 128                          // packed codebook offset in ws (bytes)
#define E2_OFF (P_OFF + KEMB * 128)        // ||e||^2 array offset

using bf16x8 = __attribute__((ext_vector_type(8))) short;
using f32x4  = __attribute__((ext_vector_type(4))) float;

__device__ __forceinline__ unsigned short f2bf(float f) {
    union { float f; unsigned u; } v; v.f = f;
    unsigned u = v.u;
    return (unsigned short)((u + 0x7FFFu + ((u >> 16) & 1u)) >> 16);  // RNE
}

__device__ __forceinline__ void gld16(const void* g, void* l) {
    __builtin_amdgcn_global_load_lds(
        (const __attribute__((address_space(1))) void*)g,
        (__attribute__((address_space(3))) void*)l, 16, 0, 0);
}

// ---- pre-pack: emb fp32 -> bf16, pre-swizzled so linear DMA == swizzled LDS.
// 16B granule g' of P-row r holds source granule g' ^ (r&7). 8 threads/row.
__global__ __launch_bounds__(256) void vq_pack(
    const float* __restrict__ emb, char* __restrict__ P, float* __restrict__ e2g)
{
    const int tid = threadIdx.x;
    const int lr = tid >> 3, cg = tid & 7;            // row-in-block, granule
    const int r = blockIdx.x * 32 + lr;
    const float4* emb4 = (const float4*)emb;
    const int q0 = r * 16 + ((cg * 2) ^ ((r & 7) << 1));   // src float4 idx
    float4 v0 = emb4[q0];
    float4 v1 = emb4[q0 + 1];
    bf16x8 o;
    o[0] = (short)f2bf(v0.x); o[1] = (short)f2bf(v0.y);
    o[2] = (short)f2bf(v0.z); o[3] = (short)f2bf(v0.w);
    o[4] = (short)f2bf(v1.x); o[5] = (short)f2bf(v1.y);
    o[6] = (short)f2bf(v1.z); o[7] = (short)f2bf(v1.w);
    *(bf16x8*)&P[r * 128 + cg * 16] = o;
    float part = v0.x*v0.x + v0.y*v0.y + v0.z*v0.z + v0.w*v0.w
               + v1.x*v1.x + v1.y*v1.y + v1.z*v1.z + v1.w*v1.w;
    #pragma unroll
    for (int m = 4; m >= 1; m >>= 1) part += __shfl_xor(part, m);  // 8-lane group
    if (cg == 0) e2g[r] = part;
}

__global__ __launch_bounds__(BLKTHREADS) void vq_main(
    const float* __restrict__ lat, const float* __restrict__ emb,
    float* __restrict__ out, unsigned* __restrict__ ticket,
    float* __restrict__ lossacc, const char* __restrict__ P,
    const char* __restrict__ e2src)
{
    __shared__ __align__(16) short ebf[2][CHUNK_BYTES / 2];  // 2 x 16384 B
    __shared__ __align__(16) float e2f[KEMB];                // 4096 B
    __shared__ int   lbk[ROWS_PER_BLOCK];                    // 256 B
    __shared__ float lloss[4];

    const int tid  = threadIdx.x;
    const int lane = tid & 63;
    const int w    = tid >> 6;      // wave 0..3
    const int l16  = lane & 15;
    const int q    = lane >> 4;     // quarter-group 0..3
    const int blk  = blockIdx.x;

    const float4* lat4 = (const float4*)lat;
    const float4* emb4 = (const float4*)emb;

    // ---- A fragments: wave's 16 rows, D=64 -> 2 frags (k=0..31, 32..63) ----
    // 16x16x32 A layout: row = lane&15, k = (lane>>4)*8 + j  (+ s*32)
    const int rowg = blk * ROWS_PER_BLOCK + w * 16 + l16;
    bf16x8 afrag[2];
    #pragma unroll
    for (int s = 0; s < 2; ++s) {
        float4 f0 = lat4[rowg * 16 + s * 8 + q * 2];
        float4 f1 = lat4[rowg * 16 + s * 8 + q * 2 + 1];
        bf16x8 a;
        a[0] = (short)f2bf(f0.x); a[1] = (short)f2bf(f0.y);
        a[2] = (short)f2bf(f0.z); a[3] = (short)f2bf(f0.w);
        a[4] = (short)f2bf(f1.x); a[5] = (short)f2bf(f1.y);
        a[6] = (short)f2bf(f1.z); a[7] = (short)f2bf(f1.w);
        afrag[s] = a;
    }
    __builtin_amdgcn_sched_barrier(0);

    // ---- prologue DMA: e2f (4 KB, 1 inst/thread) + chunk0 (4 inst/thread) ----
    gld16(e2src + tid * 16, (char*)e2f + tid * 16);
    #pragma unroll
    for (int i = 0; i < 4; ++i)
        gld16(P + tid * 16 + i * 4096, (char*)&ebf[0][0] + tid * 16 + i * 4096);
    asm volatile("s_waitcnt vmcnt(0)" ::: "memory");
    __builtin_amdgcn_s_barrier();
    __builtin_amdgcn_sched_barrier(0);

    float best[4];
    int   bk[4];
    #pragma unroll
    for (int j = 0; j < 4; ++j) { best[j] = 3.0e38f; bk[j] = 0; }

    for (int c = 0; c < NCHUNKS; ++c) {
        const int cur = c & 1;
        if (c < NCHUNKS - 1) {   // stage next chunk into other buffer
            const char* src = P + (size_t)(c + 1) * CHUNK_BYTES + tid * 16;
            char* dst = (char*)&ebf[cur ^ 1][0] + tid * 16;
            #pragma unroll
            for (int i = 0; i < 4; ++i) gld16(src + i * 4096, dst + i * 4096);
        }
        const short* eb = &ebf[cur][0];
        #pragma unroll
        for (int nt = 0; nt < KCHUNK / 16; ++nt) {
            const int kl = nt * 16 + l16;         // code row in chunk
            f32x4 acc = {0.f, 0.f, 0.f, 0.f};
            #pragma unroll
            for (int s = 0; s < 2; ++s) {
                // granule (s*4+q) ^ (kl&7)  ==> canonical k-order after swizzle
                bf16x8 b = *(const bf16x8*)&eb[kl * 64 + ((s * 32 + q * 8) ^ ((kl & 7) << 3))];
                acc = __builtin_amdgcn_mfma_f32_16x16x32_bf16(afrag[s], b, acc, 0, 0, 0);
            }
            const float e2v = e2f[c * KCHUNK + kl];
            const int   kg  = c * KCHUNK + kl;
            #pragma unroll
            for (int j = 0; j < 4; ++j) {
                float s = fmaf(-2.0f, acc[j], e2v);   // dist - ||x||^2
                bool u = s < best[j];
                best[j] = u ? s : best[j];
                bk[j]   = u ? kg : bk[j];
            }
        }
        if (c < NCHUNKS - 1) {
            asm volatile("s_waitcnt vmcnt(0)" ::: "memory");  // next chunk landed
            __builtin_amdgcn_s_barrier();                     // + all done reading
            __builtin_amdgcn_sched_barrier(0);
        }
    }

    // ---- argmin across the 16 code-columns (within each 16-lane group) ----
    // C/D layout (m89): col = lane&15, row = (lane>>4)*4 + reg
    #pragma unroll
    for (int j = 0; j < 4; ++j) {
        float v = best[j]; int k = bk[j];
        #pragma unroll
        for (int m = 8; m >= 1; m >>= 1) {
            float ov = __shfl_xor(v, m);
            int   ok = __shfl_xor(k, m);
            bool t = (ov < v) || (ov == v && ok < k);  // first-index tiebreak
            v = t ? ov : v; k = t ? ok : k;
        }
        if (l16 == 0) lbk[w * 16 + q * 4 + j] = k;
    }
    __syncthreads();

    // ---- output: quantized_st = x + (q - x), loss partial ----
    float loss = 0.f;
    {
        const int row = tid >> 2, q4 = tid & 3;   // 4 threads/row, 64 B each
        const int rg = blk * ROWS_PER_BLOCK + row;
        const int kb = lbk[row];
        float4* out4 = (float4*)out;
        #pragma unroll
        for (int j = 0; j < 4; ++j) {
            float4 x = lat4[rg * 16 + q4 * 4 + j];
            float4 qv = emb4[kb * 16 + q4 * 4 + j];
            float dx = qv.x - x.x, dy = qv.y - x.y, dz = qv.z - x.z, dw = qv.w - x.w;
            float4 o;
            o.x = x.x + dx; o.y = x.y + dy; o.z = x.z + dz; o.w = x.w + dw;
            loss += dx*dx + dy*dy + dz*dz + dw*dw;
            out4[rg * 16 + q4 * 4 + j] = o;
        }
    }
    #pragma unroll
    for (int m = 32; m >= 1; m >>= 1) loss += __shfl_down(loss, m);
    if (lane == 0) lloss[w] = loss;
    __syncthreads();

    if (tid == 0) {
        float part = lloss[0] + lloss[1] + lloss[2] + lloss[3];
        float old = atomicAdd(lossacc, part);       // device-scope
        asm volatile("" :: "v"(old) : "memory");    // force completion first
        unsigned t = atomicAdd(ticket, 1u);
        if (t == NBLOCKS - 1) {                     // last block: all adds visible
            float tot = atomicAdd(lossacc, 0.0f);   // coherent read
            out[NROWS * DDIM] = tot * (1.25f / (float)(NROWS * DDIM));
        }
    }
}

extern "C" void kernel_launch(void* const* d_in, const int* in_sizes, int n_in,
                              void* d_out, int out_size, void* d_ws, size_t ws_size,
                              hipStream_t stream)
{
    const float* lat = (const float*)d_in[0];
    const float* emb = (const float*)d_in[1];
    float* out = (float*)d_out;
    unsigned* ticket = (unsigned*)d_ws;             // ws[0]
    float* lossacc = (float*)((char*)d_ws + 4);     // ws[4..8)
    char* P   = (char*)d_ws + P_OFF;                // packed swizzled bf16 codebook
    char* e2b = (char*)d_ws + E2_OFF;               // ||e||^2 (fp32, 4 KB)

    hipMemsetAsync(d_ws, 0, 8, stream);             // zero ticket + loss accum
    vq_pack<<<KEMB / 32, 256, 0, stream>>>(emb, P, (float*)e2b);
    vq_main<<<NBLOCKS, BLKTHREADS, 0, stream>>>(lat, emb, out, ticket, lossacc,
                                                (const char*)P, (const char*)e2b);
}